// Round 8
// baseline (3771.989 us; speedup 1.0000x reference)
//
#include <hip/hip_runtime.h>

#define DEVFN __device__ __forceinline__

static inline int ceil_div(int a, int b) { return (a + b - 1) / b; }

// ---------------------------------------------------------------------------
// Farthest point sampling — SINGLE WAVE per batch, packed-key argmax.
// key = (fp32_dist_bits << 32) | ~idx  (positive double; unsigned==double
// ordering). Per-lane pairwise v_max_f64 tree over PPL candidates, then one
// LDS atomicMax (ds_max_u64) across the 64 lanes into a ping-ponged slot.
// First-occurrence tie-break: equal dist -> larger ~idx -> smaller idx.
// Winning keys are always normal doubles (dd=0 candidates can never win).
// Distance arithmetic exact fp32 (no FMA contraction) to match numpy.
// ---------------------------------------------------------------------------
template<int N>
__global__ __launch_bounds__(64) void fps_kernel(const float* __restrict__ xyz, int M,
                                                 int* __restrict__ out_idx,
                                                 float* __restrict__ nxout)
{
    constexpr int PPL = N / 64;
    int b = blockIdx.x, lane = threadIdx.x;
    __shared__ float4 sp[N];
    __shared__ unsigned long long slot[2];
    const float* p = xyz + (size_t)b * N * 3;
    float px[PPL], py[PPL], pz[PPL], dd[PPL];
    unsigned lo[PPL];
    #pragma unroll
    for (int j = 0; j < PPL; ++j) {
        int idx = lane + 64 * j;
        px[j] = p[idx*3+0]; py[j] = p[idx*3+1]; pz[j] = p[idx*3+2];
        sp[idx] = make_float4(px[j], py[j], pz[j], 0.f);
        dd[j] = 1e10f;
        lo[j] = ~(unsigned)idx;
    }
    if (lane == 0) { slot[0] = 0ull; slot[1] = 0ull; }
    __syncthreads();
    int far = 0;
    for (int s = 0; s < M; ++s) {
        float4 c4 = sp[far];
        if (lane == 0) {
            out_idx[(size_t)b*M + s] = far;
            nxout[((size_t)b*M + s)*3 + 0] = c4.x;
            nxout[((size_t)b*M + s)*3 + 1] = c4.y;
            nxout[((size_t)b*M + s)*3 + 2] = c4.z;
        }
        double cand[PPL];
        #pragma unroll
        for (int j = 0; j < PPL; ++j) {
            float dx = __fsub_rn(px[j], c4.x);
            float dy = __fsub_rn(py[j], c4.y);
            float dz = __fsub_rn(pz[j], c4.z);
            float d  = __fadd_rn(__fadd_rn(__fmul_rn(dx,dx), __fmul_rn(dy,dy)),
                                 __fmul_rn(dz,dz));
            float nd = fminf(dd[j], d);
            dd[j] = nd;
            cand[j] = __hiloint2double(__float_as_int(nd), (int)lo[j]);
        }
        #pragma unroll
        for (int st = PPL/2; st > 0; st >>= 1)
            #pragma unroll
            for (int j = 0; j < PPL; ++j)
                if (j < st) cand[j] = fmax(cand[j], cand[j + st]);
        int cur = s & 1;
        atomicMax(&slot[cur], (unsigned long long)__double_as_longlong(cand[0]));
        __syncthreads();
        unsigned long long k = slot[cur];   // all lanes read (in-order DS)
        if (lane == 0) slot[cur] = 0ull;    // reset for step s+2
        far = (int)(~(unsigned)k);
    }
}

// ---------------------------------------------------------------------------
// Ball query (unchanged).
// ---------------------------------------------------------------------------
__global__ void ballquery_kernel(const float* __restrict__ xyz,
                                 const float* __restrict__ new_xyz,
                                 int* __restrict__ gi,
                                 int B, int N, int M, int K, float r2)
{
    int t = blockIdx.x * blockDim.x + threadIdx.x;
    if (t >= B * M) return;
    int b = t / M;
    const float* p = xyz + (size_t)b * N * 3;
    float cx = new_xyz[t*3+0], cy = new_xyz[t*3+1], cz = new_xyz[t*3+2];
    int* out = gi + (size_t)t * K;
    int cnt = 0, first = 0;
    bool havefirst = false;
    for (int i = 0; i < N; ++i) {
        float dx = __fsub_rn(p[i*3+0], cx);
        float dy = __fsub_rn(p[i*3+1], cy);
        float dz = __fsub_rn(p[i*3+2], cz);
        float d  = __fadd_rn(__fadd_rn(__fmul_rn(dx,dx), __fmul_rn(dy,dy)),
                             __fmul_rn(dz,dz));
        if (d <= r2) {
            if (!havefirst) { first = i; havefirst = true; }
            out[cnt++] = i;
            if (cnt == K) break;
        }
    }
    for (; cnt < K; ++cnt) out[cnt] = first;
}

DEVFN float f4_elem(const float4& v, int u) {  // u is compile-time after unroll
    return u == 0 ? v.x : u == 1 ? v.y : u == 2 ? v.z : v.w;
}

// ===========================================================================
// Per-layer MLP kernels over GLOBAL activations (L2/L3-resident), no LDS, no
// barriers (unchanged from R7). lane = row; wave wv (readfirstlane -> scalar)
// owns CO/4 cols so weights/bias are s_loads; activations col-major [C][Rc].
// ===========================================================================

// Layer 1 with fused gather + centering. feats rows are row-major gathered.
template<int CF, int CO, int KPTS>
__global__ __launch_bounds__(256) void sa_l1_kernel(
    const float* __restrict__ xyz, const float* __restrict__ feats,
    const float* __restrict__ new_xyz, const int* __restrict__ gi,
    const float* __restrict__ w, const float* __restrict__ bias,
    float* __restrict__ out,            // [CO][Rc] col-major, chunk-local
    int N, int M, int row0, int Rc)
{
    constexpr int WCH = CO / 4;
    const int lane = threadIdx.x & 63;
    const int wv   = __builtin_amdgcn_readfirstlane(threadIdx.x >> 6);
    const int rl   = blockIdx.x * 64 + lane;
    const int row  = row0 + rl;
    const int cent = row / KPTS;
    const int b    = cent / M;
    const int idx  = gi[row];
    const float* pp  = xyz + ((size_t)b*N + idx)*3;
    const float* cc3 = new_xyz + (size_t)cent*3;
    float a0 = __fsub_rn(pp[0], cc3[0]);
    float a1 = __fsub_rn(pp[1], cc3[1]);
    float a2 = __fsub_rn(pp[2], cc3[2]);
    const float* frow = feats + ((size_t)b*N + idx)*CF;
    const float* wcol = w + wv*WCH;
    const float* bcol = bias + wv*WCH;
    float acc[WCH];
    #pragma unroll
    for (int j = 0; j < WCH; ++j) acc[j] = bcol[j];
    #pragma unroll
    for (int j = 0; j < WCH; ++j) acc[j] += a0 * wcol[0*CO + j];
    #pragma unroll
    for (int j = 0; j < WCH; ++j) acc[j] += a1 * wcol[1*CO + j];
    #pragma unroll
    for (int j = 0; j < WCH; ++j) acc[j] += a2 * wcol[2*CO + j];
    constexpr int CF4 = CF & ~3;
    #pragma unroll 2
    for (int cc = 0; cc < CF4; cc += 4) {
        float4 a4 = *(const float4*)(frow + cc);
        #pragma unroll
        for (int u = 0; u < 4; ++u) {
            float a = f4_elem(a4, u);
            #pragma unroll
            for (int j = 0; j < WCH; ++j)
                acc[j] += a * wcol[(size_t)(3 + cc + u)*CO + j];
        }
    }
    #pragma unroll
    for (int f = CF4; f < CF; ++f) {
        float a = frow[f];
        #pragma unroll
        for (int j = 0; j < WCH; ++j)
            acc[j] += a * wcol[(size_t)(3 + f)*CO + j];
    }
    float* ocol = out + (size_t)wv*WCH*Rc + rl;
    #pragma unroll
    for (int j = 0; j < WCH; ++j) ocol[(size_t)j*Rc] = fmaxf(acc[j], 0.f);
}

// Middle layer: col-major in, col-major out.
template<int CI, int CO>
__global__ __launch_bounds__(256) void layer_cm_kernel(
    const float* __restrict__ act,      // [CI][Rc]
    const float* __restrict__ w, const float* __restrict__ bias,
    float* __restrict__ out,            // [CO][Rc]
    int Rc)
{
    constexpr int WCH = CO / 4;
    const int lane = threadIdx.x & 63;
    const int wv   = __builtin_amdgcn_readfirstlane(threadIdx.x >> 6);
    const int rl   = blockIdx.x * 64 + lane;
    const float* wcol = w + wv*WCH;
    const float* bcol = bias + wv*WCH;
    float acc[WCH];
    #pragma unroll
    for (int j = 0; j < WCH; ++j) acc[j] = bcol[j];
    const float* ap = act + rl;
    #pragma unroll 4
    for (int ci = 0; ci < CI; ++ci) {
        float a = ap[(size_t)ci*Rc];
        #pragma unroll
        for (int j = 0; j < WCH; ++j)
            acc[j] += a * wcol[(size_t)ci*CO + j];
    }
    float* ocol = out + (size_t)wv*WCH*Rc + rl;
    #pragma unroll
    for (int j = 0; j < WCH; ++j) ocol[(size_t)j*Rc] = fmaxf(acc[j], 0.f);
}

// Final layer: relu then max over each KPTS-lane group (shfl butterfly);
// group leaders store the centroid's CO/4 slice to the row-major output.
template<int CI, int CO, int KPTS>
__global__ __launch_bounds__(256) void layer_max_cm_kernel(
    const float* __restrict__ act,      // [CI][Rc]
    const float* __restrict__ w, const float* __restrict__ bias,
    float* __restrict__ fout,           // [cent][CO] row-major (global)
    int row0, int Rc)
{
    constexpr int WCH = CO / 4;
    const int lane = threadIdx.x & 63;
    const int wv   = __builtin_amdgcn_readfirstlane(threadIdx.x >> 6);
    const int rl   = blockIdx.x * 64 + lane;
    const float* wcol = w + wv*WCH;
    const float* bcol = bias + wv*WCH;
    float acc[WCH];
    #pragma unroll
    for (int j = 0; j < WCH; ++j) acc[j] = bcol[j];
    const float* ap = act + rl;
    #pragma unroll 4
    for (int ci = 0; ci < CI; ++ci) {
        float a = ap[(size_t)ci*Rc];
        #pragma unroll
        for (int j = 0; j < WCH; ++j)
            acc[j] += a * wcol[(size_t)ci*CO + j];
    }
    #pragma unroll
    for (int j = 0; j < WCH; ++j) acc[j] = fmaxf(acc[j], 0.f);
    #pragma unroll
    for (int off = KPTS/2; off > 0; off >>= 1)
        #pragma unroll
        for (int j = 0; j < WCH; ++j)
            acc[j] = fmaxf(acc[j], __shfl_xor(acc[j], off));
    if ((lane & (KPTS-1)) == 0) {
        int cent = (row0 + rl) / KPTS;
        float* op = fout + (size_t)cent*CO + wv*WCH;
        #pragma unroll
        for (int j4 = 0; j4 < WCH; j4 += 4) {
            float4 v;
            v.x = acc[j4+0]; v.y = acc[j4+1]; v.z = acc[j4+2]; v.w = acc[j4+3];
            *(float4*)(op + j4) = v;
        }
    }
}

// ---------------------------------------------------------------------------
// concat [R,3] ++ [R,CF] -> [R,3+CF]
// ---------------------------------------------------------------------------
__global__ void concat_kernel(const float* __restrict__ a, const float* __restrict__ f,
                              float* __restrict__ out, int R, int CF)
{
    int C = CF + 3;
    int t = blockIdx.x * blockDim.x + threadIdx.x;
    if (t >= R * C) return;
    int r = t / C, c = t % C;
    out[t] = (c < 3) ? a[r*3 + c] : f[(size_t)r * CF + (c - 3)];
}

// ---------------------------------------------------------------------------
// Tiled fp32 GEMM, 64x64 tile / 4x4 micro (small shapes + FC head).
// ---------------------------------------------------------------------------
template<int RELU, int HASB>
__global__ __launch_bounds__(256) void gemm_kernel(
    const float* __restrict__ A, const float* __restrict__ W,
    const float* __restrict__ bias, float* __restrict__ Cc,
    int Mr, int Nc, int Kd)
{
    __shared__ float As[64][17];
    __shared__ float Ws[16][65];
    int tx = threadIdx.x % 16;
    int ty = threadIdx.x / 16;
    int row0 = blockIdx.y * 64;
    int col0 = blockIdx.x * 64;
    float acc[4][4] = {};
    for (int k0 = 0; k0 < Kd; k0 += 16) {
        for (int t = threadIdx.x; t < 64*16; t += 256) {
            int r = t >> 4, kk = t & 15;
            int gr = row0 + r, gk = k0 + kk;
            As[r][kk] = (gr < Mr && gk < Kd) ? A[(size_t)gr * Kd + gk] : 0.f;
        }
        for (int t = threadIdx.x; t < 16*64; t += 256) {
            int kk = t >> 6, c = t & 63;
            int gk = k0 + kk, gc = col0 + c;
            Ws[kk][c] = (gk < Kd && gc < Nc) ? W[(size_t)gk * Nc + gc] : 0.f;
        }
        __syncthreads();
        #pragma unroll
        for (int kk = 0; kk < 16; ++kk) {
            float av[4], wv[4];
            #pragma unroll
            for (int i = 0; i < 4; i++) av[i] = As[ty*4+i][kk];
            #pragma unroll
            for (int j = 0; j < 4; j++) wv[j] = Ws[kk][tx*4+j];
            #pragma unroll
            for (int i = 0; i < 4; i++)
                #pragma unroll
                for (int j = 0; j < 4; j++)
                    acc[i][j] += av[i] * wv[j];
        }
        __syncthreads();
    }
    #pragma unroll
    for (int i = 0; i < 4; i++) {
        int gr = row0 + ty*4 + i;
        if (gr >= Mr) continue;
        #pragma unroll
        for (int j = 0; j < 4; j++) {
            int gc = col0 + tx*4 + j;
            if (gc >= Nc) continue;
            float v = acc[i][j];
            if (HASB) v += bias[gc];
            if (RELU) v = fmaxf(v, 0.f);
            Cc[(size_t)gr * Nc + gc] = v;
        }
    }
}

// ---------------------------------------------------------------------------
// Tiled fp32 GEMM, 128x128 tile / 8x8 micro (strided fragment mapping).
// ---------------------------------------------------------------------------
template<int RELU, int HASB>
__global__ __launch_bounds__(256, 2) void gemm128_kernel(
    const float* __restrict__ A, const float* __restrict__ W,
    const float* __restrict__ bias, float* __restrict__ Cc,
    int Mr, int Nc, int Kd)
{
    __shared__ float As[128][17];
    __shared__ float Ws[16][132];
    int tx = threadIdx.x % 16;
    int ty = threadIdx.x / 16;
    int row0 = blockIdx.y * 128;
    int col0 = blockIdx.x * 128;
    float acc[8][8] = {};
    for (int k0 = 0; k0 < Kd; k0 += 16) {
        for (int t = threadIdx.x; t < 128*16; t += 256) {
            int r = t >> 4, kk = t & 15;
            int gr = row0 + r, gk = k0 + kk;
            As[r][kk] = (gr < Mr && gk < Kd) ? A[(size_t)gr * Kd + gk] : 0.f;
        }
        for (int t = threadIdx.x; t < 16*128; t += 256) {
            int kk = t >> 7, c = t & 127;
            int gk = k0 + kk, gc = col0 + c;
            Ws[kk][c] = (gk < Kd && gc < Nc) ? W[(size_t)gk * Nc + gc] : 0.f;
        }
        __syncthreads();
        #pragma unroll
        for (int kk = 0; kk < 16; ++kk) {
            float av[8], wv[8];
            #pragma unroll
            for (int i = 0; i < 8; i++) av[i] = As[ty + 16*i][kk];
            #pragma unroll
            for (int j = 0; j < 8; j++) wv[j] = Ws[kk][tx + 16*j];
            #pragma unroll
            for (int i = 0; i < 8; i++)
                #pragma unroll
                for (int j = 0; j < 8; j++)
                    acc[i][j] += av[i] * wv[j];
        }
        __syncthreads();
    }
    #pragma unroll
    for (int i = 0; i < 8; i++) {
        int gr = row0 + ty + 16*i;
        if (gr >= Mr) continue;
        #pragma unroll
        for (int j = 0; j < 8; j++) {
            int gc = col0 + tx + 16*j;
            if (gc >= Nc) continue;
            float v = acc[i][j];
            if (HASB) v += bias[gc];
            if (RELU) v = fmaxf(v, 0.f);
            Cc[(size_t)gr * Nc + gc] = v;
        }
    }
}

// ---------------------------------------------------------------------------
// Max over P points: in [B,P,C] -> out [B,C]
// ---------------------------------------------------------------------------
__global__ void rowmax_kernel(const float* __restrict__ in, float* __restrict__ out,
                              int B, int P, int C)
{
    int t = blockIdx.x * blockDim.x + threadIdx.x;
    if (t >= B * C) return;
    int b = t / C, c = t % C;
    const float* p = in + (size_t)b * P * C + c;
    float mx = p[0];
    for (int i = 1; i < P; ++i) mx = fmaxf(mx, p[(size_t)i * C]);
    out[t] = mx;
}

// ---------------------------------------------------------------------------
extern "C" void kernel_launch(void* const* d_in, const int* in_sizes, int n_in,
                              void* d_out, int out_size, void* d_ws, size_t ws_size,
                              hipStream_t stream)
{
    const float* xyz    = (const float*)d_in[0];
    const float* points = (const float*)d_in[1];
    const float* w1a = (const float*)d_in[2];  const float* b1a = (const float*)d_in[3];
    const float* w1b = (const float*)d_in[4];  const float* b1b = (const float*)d_in[5];
    const float* w1c = (const float*)d_in[6];  const float* b1c = (const float*)d_in[7];
    const float* w2a = (const float*)d_in[8];  const float* b2a = (const float*)d_in[9];
    const float* w2b = (const float*)d_in[10]; const float* b2b = (const float*)d_in[11];
    const float* w2c = (const float*)d_in[12]; const float* b2c = (const float*)d_in[13];
    const float* w3a = (const float*)d_in[14]; const float* b3a = (const float*)d_in[15];
    const float* w3b = (const float*)d_in[16]; const float* b3b = (const float*)d_in[17];
    const float* w3c = (const float*)d_in[18]; const float* b3c = (const float*)d_in[19];
    const float* lin1 = (const float*)d_in[20];
    const float* lin2 = (const float*)d_in[21];
    const float* clsw = (const float*)d_in[22];
    const float* clsb = (const float*)d_in[23];

    char* ws = (char*)d_ws;
    size_t off = 0;
    auto alloc = [&](size_t bytes) -> void* {
        void* p = ws + off;
        off += (bytes + 255) & ~(size_t)255;
        return p;
    };
    int*   fps1 = (int*)  alloc((size_t)32*512*4);
    float* nx1  = (float*)alloc((size_t)32*512*3*4);
    int*   gi1  = (int*)  alloc((size_t)32*512*32*4);
    float* f1   = (float*)alloc((size_t)32*512*128*4);
    int*   fps2 = (int*)  alloc((size_t)32*128*4);
    float* nx2  = (float*)alloc((size_t)32*128*3*4);
    int*   gi2  = (int*)  alloc((size_t)32*128*64*4);
    float* f2   = (float*)alloc((size_t)32*128*256*4);
    float* g3   = (float*)alloc((size_t)4096*259*4);
    float* h3a  = (float*)alloc((size_t)4096*256*4);
    float* h3b  = (float*)alloc((size_t)4096*512*4);
    float* h3c  = (float*)alloc((size_t)4096*1024*4);
    float* f3   = (float*)alloc((size_t)32*1024*4);
    float* fc1  = (float*)alloc((size_t)32*512*4);
    float* fc2  = (float*)alloc((size_t)32*256*4);

    // Ping-pong activation buffers for the per-layer SA pipeline, sized from
    // the remaining workspace (chunked row processing keeps footprint bounded).
    size_t avail = (ws_size > off + 512) ? (ws_size - off - 512) : 0;
    size_t bufcap = avail / 2;
    if (bufcap > (size_t)33554432) bufcap = 33554432;   // 65536 rows x 128 ch
    float* bufA = (float*)alloc(bufcap);
    float* bufB = (float*)alloc(bufcap);

    // ---- SA1: N=1024 -> M=512, r=0.2, K=32, MLP 6->64->64->128
    fps_kernel<1024><<<32, 64, 0, stream>>>(xyz, 512, fps1, nx1);
    ballquery_kernel<<<ceil_div(32*512, 256), 256, 0, stream>>>(
        xyz, nx1, gi1, 32, 1024, 512, 32, (float)(0.2*0.2));
    {
        const int rows = 32*512*32;                     // 524288
        int ch = (int)((bufcap / (64*4)) & ~(size_t)63);
        if (ch > rows) ch = rows;
        if (ch < 64) ch = 64;
        for (int r0 = 0; r0 < rows; r0 += ch) {
            int rc = rows - r0 < ch ? rows - r0 : ch;
            int nb = rc / 64;
            sa_l1_kernel<3, 64, 32><<<nb, 256, 0, stream>>>(
                xyz, points, nx1, gi1, w1a, b1a, bufA, 1024, 512, r0, rc);
            layer_cm_kernel<64, 64><<<nb, 256, 0, stream>>>(
                bufA, w1b, b1b, bufB, rc);
            layer_max_cm_kernel<64, 128, 32><<<nb, 256, 0, stream>>>(
                bufB, w1c, b1c, f1, r0, rc);
        }
    }

    // ---- SA2: N=512 -> M=128, r=0.4, K=64, MLP 131->128->128->256
    fps_kernel<512><<<32, 64, 0, stream>>>(nx1, 128, fps2, nx2);
    ballquery_kernel<<<ceil_div(32*128, 256), 256, 0, stream>>>(
        nx1, nx2, gi2, 32, 512, 128, 64, (float)(0.4*0.4));
    {
        const int rows = 32*128*64;                     // 262144
        int ch = (int)((bufcap / (128*4)) & ~(size_t)63);
        if (ch > rows) ch = rows;
        if (ch < 64) ch = 64;
        for (int r0 = 0; r0 < rows; r0 += ch) {
            int rc = rows - r0 < ch ? rows - r0 : ch;
            int nb = rc / 64;
            sa_l1_kernel<128, 128, 64><<<nb, 256, 0, stream>>>(
                nx1, f1, nx2, gi2, w2a, b2a, bufA, 512, 128, r0, rc);
            layer_cm_kernel<128, 128><<<nb, 256, 0, stream>>>(
                bufA, w2b, b2b, bufB, rc);
            layer_max_cm_kernel<128, 256, 64><<<nb, 256, 0, stream>>>(
                bufB, w2c, b2c, f2, r0, rc);
        }
    }

    // ---- SA3 (group_all): concat [4096, 259] -> MLP 259->256->512->1024 -> max over 128
    concat_kernel<<<ceil_div(4096*259, 256), 256, 0, stream>>>(nx2, f2, g3, 4096, 256);
    {
        dim3 g(ceil_div(256, 64), ceil_div(4096, 64));
        gemm_kernel<1,1><<<g, 256, 0, stream>>>(g3, w3a, b3a, h3a, 4096, 256, 259);
    }
    {
        dim3 g(ceil_div(512, 128), ceil_div(4096, 128));
        gemm128_kernel<1,1><<<g, 256, 0, stream>>>(h3a, w3b, b3b, h3b, 4096, 512, 256);
    }
    {
        dim3 g(ceil_div(1024, 128), ceil_div(4096, 128));
        gemm128_kernel<1,1><<<g, 256, 0, stream>>>(h3b, w3c, b3c, h3c, 4096, 1024, 512);
    }
    rowmax_kernel<<<ceil_div(32*1024, 256), 256, 0, stream>>>(h3c, f3, 32, 128, 1024);

    // ---- FC head
    {
        dim3 g(ceil_div(512, 64), 1);
        gemm_kernel<1,0><<<g, 256, 0, stream>>>(f3, lin1, nullptr, fc1, 32, 512, 1024);
    }
    {
        dim3 g(ceil_div(256, 64), 1);
        gemm_kernel<1,0><<<g, 256, 0, stream>>>(fc1, lin2, nullptr, fc2, 32, 256, 512);
    }
    {
        dim3 g(1, 1);
        gemm_kernel<0,1><<<g, 256, 0, stream>>>(fc2, clsw, clsb, (float*)d_out, 32, 40, 256);
    }
}

// Round 9
// 1999.070 us; speedup vs baseline: 1.8869x; 1.8869x over previous
//
#include <hip/hip_runtime.h>

#define DEVFN __device__ __forceinline__

static inline int ceil_div(int a, int b) { return (a + b - 1) / b; }

// ---------------------------------------------------------------------------
// DPP-based 64-lane max reduction step for a packed double key.
// ---------------------------------------------------------------------------
template<int CTRL>
DEVFN double dpp_max_step(double v)
{
    int lo = __double2loint(v), hi = __double2hiint(v);
    int tlo = __builtin_amdgcn_update_dpp(lo, lo, CTRL, 0xF, 0xF, false);
    int thi = __builtin_amdgcn_update_dpp(hi, hi, CTRL, 0xF, 0xF, false);
    return fmax(v, __hiloint2double(thi, tlo));
}

// ---------------------------------------------------------------------------
// Farthest point sampling — SINGLE WAVE per batch, packed-key argmax.
// key = (fp32_dist_bits << 32) | ~idx  (positive double; double ordering ==
// unsigned ordering). Per-lane pairwise v_max_f64 tree over PPL candidates,
// then a 6-step DPP max reduce on the VALU (no LDS on the critical path):
// quad_perm xor1, xor2, row_ror:4, row_ror:8, row_bcast15, row_bcast31 —
// lane 63 ends with the wave max; v_readlane broadcasts it.
// First-occurrence tie-break: equal dist -> larger ~idx -> smaller idx.
// Distance arithmetic exact fp32 (no FMA contraction) to match numpy.
// ---------------------------------------------------------------------------
template<int N>
__global__ __launch_bounds__(64) void fps_kernel(const float* __restrict__ xyz, int M,
                                                 int* __restrict__ out_idx,
                                                 float* __restrict__ nxout)
{
    constexpr int PPL = N / 64;
    int b = blockIdx.x, lane = threadIdx.x;
    __shared__ float4 sp[N];
    const float* p = xyz + (size_t)b * N * 3;
    float px[PPL], py[PPL], pz[PPL], dd[PPL];
    unsigned lo[PPL];
    #pragma unroll
    for (int j = 0; j < PPL; ++j) {
        int idx = lane + 64 * j;
        px[j] = p[idx*3+0]; py[j] = p[idx*3+1]; pz[j] = p[idx*3+2];
        sp[idx] = make_float4(px[j], py[j], pz[j], 0.f);
        dd[j] = 1e10f;
        lo[j] = ~(unsigned)idx;
    }
    __syncthreads();
    int far = 0;
    for (int s = 0; s < M; ++s) {
        float4 c4 = sp[far];                      // uniform-address broadcast read
        if (lane == 0) {
            out_idx[(size_t)b*M + s] = far;
            nxout[((size_t)b*M + s)*3 + 0] = c4.x;
            nxout[((size_t)b*M + s)*3 + 1] = c4.y;
            nxout[((size_t)b*M + s)*3 + 2] = c4.z;
        }
        double cand[PPL];
        #pragma unroll
        for (int j = 0; j < PPL; ++j) {
            float dx = __fsub_rn(px[j], c4.x);
            float dy = __fsub_rn(py[j], c4.y);
            float dz = __fsub_rn(pz[j], c4.z);
            float d  = __fadd_rn(__fadd_rn(__fmul_rn(dx,dx), __fmul_rn(dy,dy)),
                                 __fmul_rn(dz,dz));
            float nd = fminf(dd[j], d);
            dd[j] = nd;
            cand[j] = __hiloint2double(__float_as_int(nd), (int)lo[j]);
        }
        #pragma unroll
        for (int st = PPL/2; st > 0; st >>= 1)
            #pragma unroll
            for (int j = 0; j < PPL; ++j)
                if (j < st) cand[j] = fmax(cand[j], cand[j + st]);
        double v = cand[0];
        v = dpp_max_step<0xB1>(v);    // quad_perm [1,0,3,2]  (xor 1)
        v = dpp_max_step<0x4E>(v);    // quad_perm [2,3,0,1]  (xor 2)
        v = dpp_max_step<0x124>(v);   // row_ror:4
        v = dpp_max_step<0x128>(v);   // row_ror:8  -> row uniform
        v = dpp_max_step<0x142>(v);   // row_bcast15
        v = dpp_max_step<0x143>(v);   // row_bcast31 -> lane 63 has wave max
        int wlo = __builtin_amdgcn_readlane(__double2loint(v), 63);
        far = (int)(~(unsigned)wlo);
    }
}

// ---------------------------------------------------------------------------
// Ball query (unchanged).
// ---------------------------------------------------------------------------
__global__ void ballquery_kernel(const float* __restrict__ xyz,
                                 const float* __restrict__ new_xyz,
                                 int* __restrict__ gi,
                                 int B, int N, int M, int K, float r2)
{
    int t = blockIdx.x * blockDim.x + threadIdx.x;
    if (t >= B * M) return;
    int b = t / M;
    const float* p = xyz + (size_t)b * N * 3;
    float cx = new_xyz[t*3+0], cy = new_xyz[t*3+1], cz = new_xyz[t*3+2];
    int* out = gi + (size_t)t * K;
    int cnt = 0, first = 0;
    bool havefirst = false;
    for (int i = 0; i < N; ++i) {
        float dx = __fsub_rn(p[i*3+0], cx);
        float dy = __fsub_rn(p[i*3+1], cy);
        float dz = __fsub_rn(p[i*3+2], cz);
        float d  = __fadd_rn(__fadd_rn(__fmul_rn(dx,dx), __fmul_rn(dy,dy)),
                             __fmul_rn(dz,dz));
        if (d <= r2) {
            if (!havefirst) { first = i; havefirst = true; }
            out[cnt++] = i;
            if (cnt == K) break;
        }
    }
    for (; cnt < K; ++cnt) out[cnt] = first;
}

DEVFN float f4_elem(const float4& v, int u) {  // u is compile-time after unroll
    return u == 0 ? v.x : u == 1 ? v.y : u == 2 ? v.z : v.w;
}

// ===========================================================================
// Per-layer MLP kernels over GLOBAL activations (L2/L3-resident), no LDS, no
// barriers (unchanged from R7). lane = row; wave wv (readfirstlane -> scalar)
// owns CO/4 cols so weights/bias are s_loads; activations col-major [C][Rc].
// ===========================================================================

// Layer 1 with fused gather + centering. feats rows are row-major gathered.
template<int CF, int CO, int KPTS>
__global__ __launch_bounds__(256) void sa_l1_kernel(
    const float* __restrict__ xyz, const float* __restrict__ feats,
    const float* __restrict__ new_xyz, const int* __restrict__ gi,
    const float* __restrict__ w, const float* __restrict__ bias,
    float* __restrict__ out,            // [CO][Rc] col-major, chunk-local
    int N, int M, int row0, int Rc)
{
    constexpr int WCH = CO / 4;
    const int lane = threadIdx.x & 63;
    const int wv   = __builtin_amdgcn_readfirstlane(threadIdx.x >> 6);
    const int rl   = blockIdx.x * 64 + lane;
    const int row  = row0 + rl;
    const int cent = row / KPTS;
    const int b    = cent / M;
    const int idx  = gi[row];
    const float* pp  = xyz + ((size_t)b*N + idx)*3;
    const float* cc3 = new_xyz + (size_t)cent*3;
    float a0 = __fsub_rn(pp[0], cc3[0]);
    float a1 = __fsub_rn(pp[1], cc3[1]);
    float a2 = __fsub_rn(pp[2], cc3[2]);
    const float* frow = feats + ((size_t)b*N + idx)*CF;
    const float* wcol = w + wv*WCH;
    const float* bcol = bias + wv*WCH;
    float acc[WCH];
    #pragma unroll
    for (int j = 0; j < WCH; ++j) acc[j] = bcol[j];
    #pragma unroll
    for (int j = 0; j < WCH; ++j) acc[j] += a0 * wcol[0*CO + j];
    #pragma unroll
    for (int j = 0; j < WCH; ++j) acc[j] += a1 * wcol[1*CO + j];
    #pragma unroll
    for (int j = 0; j < WCH; ++j) acc[j] += a2 * wcol[2*CO + j];
    constexpr int CF4 = CF & ~3;
    #pragma unroll 2
    for (int cc = 0; cc < CF4; cc += 4) {
        float4 a4 = *(const float4*)(frow + cc);
        #pragma unroll
        for (int u = 0; u < 4; ++u) {
            float a = f4_elem(a4, u);
            #pragma unroll
            for (int j = 0; j < WCH; ++j)
                acc[j] += a * wcol[(size_t)(3 + cc + u)*CO + j];
        }
    }
    #pragma unroll
    for (int f = CF4; f < CF; ++f) {
        float a = frow[f];
        #pragma unroll
        for (int j = 0; j < WCH; ++j)
            acc[j] += a * wcol[(size_t)(3 + f)*CO + j];
    }
    float* ocol = out + (size_t)wv*WCH*Rc + rl;
    #pragma unroll
    for (int j = 0; j < WCH; ++j) ocol[(size_t)j*Rc] = fmaxf(acc[j], 0.f);
}

// Middle layer: col-major in, col-major out.
template<int CI, int CO>
__global__ __launch_bounds__(256) void layer_cm_kernel(
    const float* __restrict__ act,      // [CI][Rc]
    const float* __restrict__ w, const float* __restrict__ bias,
    float* __restrict__ out,            // [CO][Rc]
    int Rc)
{
    constexpr int WCH = CO / 4;
    const int lane = threadIdx.x & 63;
    const int wv   = __builtin_amdgcn_readfirstlane(threadIdx.x >> 6);
    const int rl   = blockIdx.x * 64 + lane;
    const float* wcol = w + wv*WCH;
    const float* bcol = bias + wv*WCH;
    float acc[WCH];
    #pragma unroll
    for (int j = 0; j < WCH; ++j) acc[j] = bcol[j];
    const float* ap = act + rl;
    #pragma unroll 4
    for (int ci = 0; ci < CI; ++ci) {
        float a = ap[(size_t)ci*Rc];
        #pragma unroll
        for (int j = 0; j < WCH; ++j)
            acc[j] += a * wcol[(size_t)ci*CO + j];
    }
    float* ocol = out + (size_t)wv*WCH*Rc + rl;
    #pragma unroll
    for (int j = 0; j < WCH; ++j) ocol[(size_t)j*Rc] = fmaxf(acc[j], 0.f);
}

// Final layer: relu then max over each KPTS-lane group (shfl butterfly);
// group leaders store the centroid's CO/4 slice to the row-major output.
template<int CI, int CO, int KPTS>
__global__ __launch_bounds__(256) void layer_max_cm_kernel(
    const float* __restrict__ act,      // [CI][Rc]
    const float* __restrict__ w, const float* __restrict__ bias,
    float* __restrict__ fout,           // [cent][CO] row-major (global)
    int row0, int Rc)
{
    constexpr int WCH = CO / 4;
    const int lane = threadIdx.x & 63;
    const int wv   = __builtin_amdgcn_readfirstlane(threadIdx.x >> 6);
    const int rl   = blockIdx.x * 64 + lane;
    const float* wcol = w + wv*WCH;
    const float* bcol = bias + wv*WCH;
    float acc[WCH];
    #pragma unroll
    for (int j = 0; j < WCH; ++j) acc[j] = bcol[j];
    const float* ap = act + rl;
    #pragma unroll 4
    for (int ci = 0; ci < CI; ++ci) {
        float a = ap[(size_t)ci*Rc];
        #pragma unroll
        for (int j = 0; j < WCH; ++j)
            acc[j] += a * wcol[(size_t)ci*CO + j];
    }
    #pragma unroll
    for (int j = 0; j < WCH; ++j) acc[j] = fmaxf(acc[j], 0.f);
    #pragma unroll
    for (int off = KPTS/2; off > 0; off >>= 1)
        #pragma unroll
        for (int j = 0; j < WCH; ++j)
            acc[j] = fmaxf(acc[j], __shfl_xor(acc[j], off));
    if ((lane & (KPTS-1)) == 0) {
        int cent = (row0 + rl) / KPTS;
        float* op = fout + (size_t)cent*CO + wv*WCH;
        #pragma unroll
        for (int j4 = 0; j4 < WCH; j4 += 4) {
            float4 v;
            v.x = acc[j4+0]; v.y = acc[j4+1]; v.z = acc[j4+2]; v.w = acc[j4+3];
            *(float4*)(op + j4) = v;
        }
    }
}

// ---------------------------------------------------------------------------
// concat [R,3] ++ [R,CF] -> [R,3+CF]
// ---------------------------------------------------------------------------
__global__ void concat_kernel(const float* __restrict__ a, const float* __restrict__ f,
                              float* __restrict__ out, int R, int CF)
{
    int C = CF + 3;
    int t = blockIdx.x * blockDim.x + threadIdx.x;
    if (t >= R * C) return;
    int r = t / C, c = t % C;
    out[t] = (c < 3) ? a[r*3 + c] : f[(size_t)r * CF + (c - 3)];
}

// ---------------------------------------------------------------------------
// Tiled fp32 GEMM, 64x64 tile / 4x4 micro (small shapes + FC head).
// ---------------------------------------------------------------------------
template<int RELU, int HASB>
__global__ __launch_bounds__(256) void gemm_kernel(
    const float* __restrict__ A, const float* __restrict__ W,
    const float* __restrict__ bias, float* __restrict__ Cc,
    int Mr, int Nc, int Kd)
{
    __shared__ float As[64][17];
    __shared__ float Ws[16][65];
    int tx = threadIdx.x % 16;
    int ty = threadIdx.x / 16;
    int row0 = blockIdx.y * 64;
    int col0 = blockIdx.x * 64;
    float acc[4][4] = {};
    for (int k0 = 0; k0 < Kd; k0 += 16) {
        for (int t = threadIdx.x; t < 64*16; t += 256) {
            int r = t >> 4, kk = t & 15;
            int gr = row0 + r, gk = k0 + kk;
            As[r][kk] = (gr < Mr && gk < Kd) ? A[(size_t)gr * Kd + gk] : 0.f;
        }
        for (int t = threadIdx.x; t < 16*64; t += 256) {
            int kk = t >> 6, c = t & 63;
            int gk = k0 + kk, gc = col0 + c;
            Ws[kk][c] = (gk < Kd && gc < Nc) ? W[(size_t)gk * Nc + gc] : 0.f;
        }
        __syncthreads();
        #pragma unroll
        for (int kk = 0; kk < 16; ++kk) {
            float av[4], wv[4];
            #pragma unroll
            for (int i = 0; i < 4; i++) av[i] = As[ty*4+i][kk];
            #pragma unroll
            for (int j = 0; j < 4; j++) wv[j] = Ws[kk][tx*4+j];
            #pragma unroll
            for (int i = 0; i < 4; i++)
                #pragma unroll
                for (int j = 0; j < 4; j++)
                    acc[i][j] += av[i] * wv[j];
        }
        __syncthreads();
    }
    #pragma unroll
    for (int i = 0; i < 4; i++) {
        int gr = row0 + ty*4 + i;
        if (gr >= Mr) continue;
        #pragma unroll
        for (int j = 0; j < 4; j++) {
            int gc = col0 + tx*4 + j;
            if (gc >= Nc) continue;
            float v = acc[i][j];
            if (HASB) v += bias[gc];
            if (RELU) v = fmaxf(v, 0.f);
            Cc[(size_t)gr * Nc + gc] = v;
        }
    }
}

// ---------------------------------------------------------------------------
// Tiled fp32 GEMM, 128x128 tile / 8x8 micro (strided fragment mapping).
// ---------------------------------------------------------------------------
template<int RELU, int HASB>
__global__ __launch_bounds__(256, 2) void gemm128_kernel(
    const float* __restrict__ A, const float* __restrict__ W,
    const float* __restrict__ bias, float* __restrict__ Cc,
    int Mr, int Nc, int Kd)
{
    __shared__ float As[128][17];
    __shared__ float Ws[16][132];
    int tx = threadIdx.x % 16;
    int ty = threadIdx.x / 16;
    int row0 = blockIdx.y * 128;
    int col0 = blockIdx.x * 128;
    float acc[8][8] = {};
    for (int k0 = 0; k0 < Kd; k0 += 16) {
        for (int t = threadIdx.x; t < 128*16; t += 256) {
            int r = t >> 4, kk = t & 15;
            int gr = row0 + r, gk = k0 + kk;
            As[r][kk] = (gr < Mr && gk < Kd) ? A[(size_t)gr * Kd + gk] : 0.f;
        }
        for (int t = threadIdx.x; t < 16*128; t += 256) {
            int kk = t >> 7, c = t & 127;
            int gk = k0 + kk, gc = col0 + c;
            Ws[kk][c] = (gk < Kd && gc < Nc) ? W[(size_t)gk * Nc + gc] : 0.f;
        }
        __syncthreads();
        #pragma unroll
        for (int kk = 0; kk < 16; ++kk) {
            float av[8], wv[8];
            #pragma unroll
            for (int i = 0; i < 8; i++) av[i] = As[ty + 16*i][kk];
            #pragma unroll
            for (int j = 0; j < 8; j++) wv[j] = Ws[kk][tx + 16*j];
            #pragma unroll
            for (int i = 0; i < 8; i++)
                #pragma unroll
                for (int j = 0; j < 8; j++)
                    acc[i][j] += av[i] * wv[j];
        }
        __syncthreads();
    }
    #pragma unroll
    for (int i = 0; i < 8; i++) {
        int gr = row0 + ty + 16*i;
        if (gr >= Mr) continue;
        #pragma unroll
        for (int j = 0; j < 8; j++) {
            int gc = col0 + tx + 16*j;
            if (gc >= Nc) continue;
            float v = acc[i][j];
            if (HASB) v += bias[gc];
            if (RELU) v = fmaxf(v, 0.f);
            Cc[(size_t)gr * Nc + gc] = v;
        }
    }
}

// ---------------------------------------------------------------------------
// Max over P points: in [B,P,C] -> out [B,C]
// ---------------------------------------------------------------------------
__global__ void rowmax_kernel(const float* __restrict__ in, float* __restrict__ out,
                              int B, int P, int C)
{
    int t = blockIdx.x * blockDim.x + threadIdx.x;
    if (t >= B * C) return;
    int b = t / C, c = t % C;
    const float* p = in + (size_t)b * P * C + c;
    float mx = p[0];
    for (int i = 1; i < P; ++i) mx = fmaxf(mx, p[(size_t)i * C]);
    out[t] = mx;
}

// ---------------------------------------------------------------------------
extern "C" void kernel_launch(void* const* d_in, const int* in_sizes, int n_in,
                              void* d_out, int out_size, void* d_ws, size_t ws_size,
                              hipStream_t stream)
{
    const float* xyz    = (const float*)d_in[0];
    const float* points = (const float*)d_in[1];
    const float* w1a = (const float*)d_in[2];  const float* b1a = (const float*)d_in[3];
    const float* w1b = (const float*)d_in[4];  const float* b1b = (const float*)d_in[5];
    const float* w1c = (const float*)d_in[6];  const float* b1c = (const float*)d_in[7];
    const float* w2a = (const float*)d_in[8];  const float* b2a = (const float*)d_in[9];
    const float* w2b = (const float*)d_in[10]; const float* b2b = (const float*)d_in[11];
    const float* w2c = (const float*)d_in[12]; const float* b2c = (const float*)d_in[13];
    const float* w3a = (const float*)d_in[14]; const float* b3a = (const float*)d_in[15];
    const float* w3b = (const float*)d_in[16]; const float* b3b = (const float*)d_in[17];
    const float* w3c = (const float*)d_in[18]; const float* b3c = (const float*)d_in[19];
    const float* lin1 = (const float*)d_in[20];
    const float* lin2 = (const float*)d_in[21];
    const float* clsw = (const float*)d_in[22];
    const float* clsb = (const float*)d_in[23];

    char* ws = (char*)d_ws;
    size_t off = 0;
    auto alloc = [&](size_t bytes) -> void* {
        void* p = ws + off;
        off += (bytes + 255) & ~(size_t)255;
        return p;
    };
    int*   fps1 = (int*)  alloc((size_t)32*512*4);
    float* nx1  = (float*)alloc((size_t)32*512*3*4);
    int*   gi1  = (int*)  alloc((size_t)32*512*32*4);
    float* f1   = (float*)alloc((size_t)32*512*128*4);
    int*   fps2 = (int*)  alloc((size_t)32*128*4);
    float* nx2  = (float*)alloc((size_t)32*128*3*4);
    int*   gi2  = (int*)  alloc((size_t)32*128*64*4);
    float* f2   = (float*)alloc((size_t)32*128*256*4);
    float* g3   = (float*)alloc((size_t)4096*259*4);
    float* h3a  = (float*)alloc((size_t)4096*256*4);
    float* h3b  = (float*)alloc((size_t)4096*512*4);
    float* h3c  = (float*)alloc((size_t)4096*1024*4);
    float* f3   = (float*)alloc((size_t)32*1024*4);
    float* fc1  = (float*)alloc((size_t)32*512*4);
    float* fc2  = (float*)alloc((size_t)32*256*4);

    // Ping-pong activation buffers for the per-layer SA pipeline, sized from
    // the remaining workspace (chunked row processing keeps footprint bounded).
    size_t avail = (ws_size > off + 512) ? (ws_size - off - 512) : 0;
    size_t bufcap = avail / 2;
    if (bufcap > (size_t)33554432) bufcap = 33554432;   // 65536 rows x 128 ch
    float* bufA = (float*)alloc(bufcap);
    float* bufB = (float*)alloc(bufcap);

    // ---- SA1: N=1024 -> M=512, r=0.2, K=32, MLP 6->64->64->128
    fps_kernel<1024><<<32, 64, 0, stream>>>(xyz, 512, fps1, nx1);
    ballquery_kernel<<<ceil_div(32*512, 256), 256, 0, stream>>>(
        xyz, nx1, gi1, 32, 1024, 512, 32, (float)(0.2*0.2));
    {
        const int rows = 32*512*32;                     // 524288
        int ch = (int)((bufcap / (64*4)) & ~(size_t)63);
        if (ch > rows) ch = rows;
        if (ch < 64) ch = 64;
        for (int r0 = 0; r0 < rows; r0 += ch) {
            int rc = rows - r0 < ch ? rows - r0 : ch;
            int nb = rc / 64;
            sa_l1_kernel<3, 64, 32><<<nb, 256, 0, stream>>>(
                xyz, points, nx1, gi1, w1a, b1a, bufA, 1024, 512, r0, rc);
            layer_cm_kernel<64, 64><<<nb, 256, 0, stream>>>(
                bufA, w1b, b1b, bufB, rc);
            layer_max_cm_kernel<64, 128, 32><<<nb, 256, 0, stream>>>(
                bufB, w1c, b1c, f1, r0, rc);
        }
    }

    // ---- SA2: N=512 -> M=128, r=0.4, K=64, MLP 131->128->128->256
    fps_kernel<512><<<32, 64, 0, stream>>>(nx1, 128, fps2, nx2);
    ballquery_kernel<<<ceil_div(32*128, 256), 256, 0, stream>>>(
        nx1, nx2, gi2, 32, 512, 128, 64, (float)(0.4*0.4));
    {
        const int rows = 32*128*64;                     // 262144
        int ch = (int)((bufcap / (128*4)) & ~(size_t)63);
        if (ch > rows) ch = rows;
        if (ch < 64) ch = 64;
        for (int r0 = 0; r0 < rows; r0 += ch) {
            int rc = rows - r0 < ch ? rows - r0 : ch;
            int nb = rc / 64;
            sa_l1_kernel<128, 128, 64><<<nb, 256, 0, stream>>>(
                nx1, f1, nx2, gi2, w2a, b2a, bufA, 512, 128, r0, rc);
            layer_cm_kernel<128, 128><<<nb, 256, 0, stream>>>(
                bufA, w2b, b2b, bufB, rc);
            layer_max_cm_kernel<128, 256, 64><<<nb, 256, 0, stream>>>(
                bufB, w2c, b2c, f2, r0, rc);
        }
    }

    // ---- SA3 (group_all): concat [4096, 259] -> MLP 259->256->512->1024 -> max over 128
    concat_kernel<<<ceil_div(4096*259, 256), 256, 0, stream>>>(nx2, f2, g3, 4096, 256);
    {
        dim3 g(ceil_div(256, 64), ceil_div(4096, 64));
        gemm_kernel<1,1><<<g, 256, 0, stream>>>(g3, w3a, b3a, h3a, 4096, 256, 259);
    }
    {
        dim3 g(ceil_div(512, 128), ceil_div(4096, 128));
        gemm128_kernel<1,1><<<g, 256, 0, stream>>>(h3a, w3b, b3b, h3b, 4096, 512, 256);
    }
    {
        dim3 g(ceil_div(1024, 128), ceil_div(4096, 128));
        gemm128_kernel<1,1><<<g, 256, 0, stream>>>(h3b, w3c, b3c, h3c, 4096, 1024, 512);
    }
    rowmax_kernel<<<ceil_div(32*1024, 256), 256, 0, stream>>>(h3c, f3, 32, 128, 1024);

    // ---- FC head
    {
        dim3 g(ceil_div(512, 64), 1);
        gemm_kernel<1,0><<<g, 256, 0, stream>>>(f3, lin1, nullptr, fc1, 32, 512, 1024);
    }
    {
        dim3 g(ceil_div(256, 64), 1);
        gemm_kernel<1,0><<<g, 256, 0, stream>>>(fc1, lin2, nullptr, fc2, 32, 256, 512);
    }
    {
        dim3 g(1, 1);
        gemm_kernel<0,1><<<g, 256, 0, stream>>>(fc2, clsw, clsb, (float*)d_out, 32, 40, 256);
    }
}

// Round 10
// 1927.568 us; speedup vs baseline: 1.9569x; 1.0371x over previous
//
#include <hip/hip_runtime.h>

#define DEVFN __device__ __forceinline__

static inline int ceil_div(int a, int b) { return (a + b - 1) / b; }

// ---------------------------------------------------------------------------
// DPP-based 64-lane max reduction step for a packed double key.
// ---------------------------------------------------------------------------
template<int CTRL>
DEVFN double dpp_max_step(double v)
{
    int lo = __double2loint(v), hi = __double2hiint(v);
    int tlo = __builtin_amdgcn_update_dpp(lo, lo, CTRL, 0xF, 0xF, false);
    int thi = __builtin_amdgcn_update_dpp(hi, hi, CTRL, 0xF, 0xF, false);
    return fmax(v, __hiloint2double(thi, tlo));
}

// ---------------------------------------------------------------------------
// Farthest point sampling — SINGLE WAVE per batch, packed-key argmax with
// 6-step DPP max reduce (unchanged from R9; 202 µs @ N=1024).
// ---------------------------------------------------------------------------
template<int N>
__global__ __launch_bounds__(64) void fps_kernel(const float* __restrict__ xyz, int M,
                                                 int* __restrict__ out_idx,
                                                 float* __restrict__ nxout)
{
    constexpr int PPL = N / 64;
    int b = blockIdx.x, lane = threadIdx.x;
    __shared__ float4 sp[N];
    const float* p = xyz + (size_t)b * N * 3;
    float px[PPL], py[PPL], pz[PPL], dd[PPL];
    unsigned lo[PPL];
    #pragma unroll
    for (int j = 0; j < PPL; ++j) {
        int idx = lane + 64 * j;
        px[j] = p[idx*3+0]; py[j] = p[idx*3+1]; pz[j] = p[idx*3+2];
        sp[idx] = make_float4(px[j], py[j], pz[j], 0.f);
        dd[j] = 1e10f;
        lo[j] = ~(unsigned)idx;
    }
    __syncthreads();
    int far = 0;
    for (int s = 0; s < M; ++s) {
        float4 c4 = sp[far];                      // uniform-address broadcast read
        if (lane == 0) {
            out_idx[(size_t)b*M + s] = far;
            nxout[((size_t)b*M + s)*3 + 0] = c4.x;
            nxout[((size_t)b*M + s)*3 + 1] = c4.y;
            nxout[((size_t)b*M + s)*3 + 2] = c4.z;
        }
        double cand[PPL];
        #pragma unroll
        for (int j = 0; j < PPL; ++j) {
            float dx = __fsub_rn(px[j], c4.x);
            float dy = __fsub_rn(py[j], c4.y);
            float dz = __fsub_rn(pz[j], c4.z);
            float d  = __fadd_rn(__fadd_rn(__fmul_rn(dx,dx), __fmul_rn(dy,dy)),
                                 __fmul_rn(dz,dz));
            float nd = fminf(dd[j], d);
            dd[j] = nd;
            cand[j] = __hiloint2double(__float_as_int(nd), (int)lo[j]);
        }
        #pragma unroll
        for (int st = PPL/2; st > 0; st >>= 1)
            #pragma unroll
            for (int j = 0; j < PPL; ++j)
                if (j < st) cand[j] = fmax(cand[j], cand[j + st]);
        double v = cand[0];
        v = dpp_max_step<0xB1>(v);    // quad_perm xor1
        v = dpp_max_step<0x4E>(v);    // quad_perm xor2
        v = dpp_max_step<0x124>(v);   // row_ror:4
        v = dpp_max_step<0x128>(v);   // row_ror:8
        v = dpp_max_step<0x142>(v);   // row_bcast15
        v = dpp_max_step<0x143>(v);   // row_bcast31 -> lane 63 has wave max
        int wlo = __builtin_amdgcn_readlane(__double2loint(v), 63);
        far = (int)(~(unsigned)wlo);
    }
}

// ---------------------------------------------------------------------------
// Ball query (unchanged).
// ---------------------------------------------------------------------------
__global__ void ballquery_kernel(const float* __restrict__ xyz,
                                 const float* __restrict__ new_xyz,
                                 int* __restrict__ gi,
                                 int B, int N, int M, int K, float r2)
{
    int t = blockIdx.x * blockDim.x + threadIdx.x;
    if (t >= B * M) return;
    int b = t / M;
    const float* p = xyz + (size_t)b * N * 3;
    float cx = new_xyz[t*3+0], cy = new_xyz[t*3+1], cz = new_xyz[t*3+2];
    int* out = gi + (size_t)t * K;
    int cnt = 0, first = 0;
    bool havefirst = false;
    for (int i = 0; i < N; ++i) {
        float dx = __fsub_rn(p[i*3+0], cx);
        float dy = __fsub_rn(p[i*3+1], cy);
        float dz = __fsub_rn(p[i*3+2], cz);
        float d  = __fadd_rn(__fadd_rn(__fmul_rn(dx,dx), __fmul_rn(dy,dy)),
                             __fmul_rn(dz,dz));
        if (d <= r2) {
            if (!havefirst) { first = i; havefirst = true; }
            out[cnt++] = i;
            if (cnt == K) break;
        }
    }
    for (; cnt < K; ++cnt) out[cnt] = first;
}

DEVFN float f4_elem(const float4& v, int u) {  // u is compile-time after unroll
    return u == 0 ? v.x : u == 1 ? v.y : u == 2 ? v.z : v.w;
}

// ===========================================================================
// Per-layer MLP kernels over GLOBAL activations (unchanged from R9).
// ===========================================================================

template<int CF, int CO, int KPTS>
__global__ __launch_bounds__(256) void sa_l1_kernel(
    const float* __restrict__ xyz, const float* __restrict__ feats,
    const float* __restrict__ new_xyz, const int* __restrict__ gi,
    const float* __restrict__ w, const float* __restrict__ bias,
    float* __restrict__ out,            // [CO][Rc] col-major, chunk-local
    int N, int M, int row0, int Rc)
{
    constexpr int WCH = CO / 4;
    const int lane = threadIdx.x & 63;
    const int wv   = __builtin_amdgcn_readfirstlane(threadIdx.x >> 6);
    const int rl   = blockIdx.x * 64 + lane;
    const int row  = row0 + rl;
    const int cent = row / KPTS;
    const int b    = cent / M;
    const int idx  = gi[row];
    const float* pp  = xyz + ((size_t)b*N + idx)*3;
    const float* cc3 = new_xyz + (size_t)cent*3;
    float a0 = __fsub_rn(pp[0], cc3[0]);
    float a1 = __fsub_rn(pp[1], cc3[1]);
    float a2 = __fsub_rn(pp[2], cc3[2]);
    const float* frow = feats + ((size_t)b*N + idx)*CF;
    const float* wcol = w + wv*WCH;
    const float* bcol = bias + wv*WCH;
    float acc[WCH];
    #pragma unroll
    for (int j = 0; j < WCH; ++j) acc[j] = bcol[j];
    #pragma unroll
    for (int j = 0; j < WCH; ++j) acc[j] += a0 * wcol[0*CO + j];
    #pragma unroll
    for (int j = 0; j < WCH; ++j) acc[j] += a1 * wcol[1*CO + j];
    #pragma unroll
    for (int j = 0; j < WCH; ++j) acc[j] += a2 * wcol[2*CO + j];
    constexpr int CF4 = CF & ~3;
    #pragma unroll 2
    for (int cc = 0; cc < CF4; cc += 4) {
        float4 a4 = *(const float4*)(frow + cc);
        #pragma unroll
        for (int u = 0; u < 4; ++u) {
            float a = f4_elem(a4, u);
            #pragma unroll
            for (int j = 0; j < WCH; ++j)
                acc[j] += a * wcol[(size_t)(3 + cc + u)*CO + j];
        }
    }
    #pragma unroll
    for (int f = CF4; f < CF; ++f) {
        float a = frow[f];
        #pragma unroll
        for (int j = 0; j < WCH; ++j)
            acc[j] += a * wcol[(size_t)(3 + f)*CO + j];
    }
    float* ocol = out + (size_t)wv*WCH*Rc + rl;
    #pragma unroll
    for (int j = 0; j < WCH; ++j) ocol[(size_t)j*Rc] = fmaxf(acc[j], 0.f);
}

template<int CI, int CO>
__global__ __launch_bounds__(256) void layer_cm_kernel(
    const float* __restrict__ act,      // [CI][Rc]
    const float* __restrict__ w, const float* __restrict__ bias,
    float* __restrict__ out,            // [CO][Rc]
    int Rc)
{
    constexpr int WCH = CO / 4;
    const int lane = threadIdx.x & 63;
    const int wv   = __builtin_amdgcn_readfirstlane(threadIdx.x >> 6);
    const int rl   = blockIdx.x * 64 + lane;
    const float* wcol = w + wv*WCH;
    const float* bcol = bias + wv*WCH;
    float acc[WCH];
    #pragma unroll
    for (int j = 0; j < WCH; ++j) acc[j] = bcol[j];
    const float* ap = act + rl;
    #pragma unroll 4
    for (int ci = 0; ci < CI; ++ci) {
        float a = ap[(size_t)ci*Rc];
        #pragma unroll
        for (int j = 0; j < WCH; ++j)
            acc[j] += a * wcol[(size_t)ci*CO + j];
    }
    float* ocol = out + (size_t)wv*WCH*Rc + rl;
    #pragma unroll
    for (int j = 0; j < WCH; ++j) ocol[(size_t)j*Rc] = fmaxf(acc[j], 0.f);
}

template<int CI, int CO, int KPTS>
__global__ __launch_bounds__(256) void layer_max_cm_kernel(
    const float* __restrict__ act,      // [CI][Rc]
    const float* __restrict__ w, const float* __restrict__ bias,
    float* __restrict__ fout,           // [cent][CO] row-major (global)
    int row0, int Rc)
{
    constexpr int WCH = CO / 4;
    const int lane = threadIdx.x & 63;
    const int wv   = __builtin_amdgcn_readfirstlane(threadIdx.x >> 6);
    const int rl   = blockIdx.x * 64 + lane;
    const float* wcol = w + wv*WCH;
    const float* bcol = bias + wv*WCH;
    float acc[WCH];
    #pragma unroll
    for (int j = 0; j < WCH; ++j) acc[j] = bcol[j];
    const float* ap = act + rl;
    #pragma unroll 4
    for (int ci = 0; ci < CI; ++ci) {
        float a = ap[(size_t)ci*Rc];
        #pragma unroll
        for (int j = 0; j < WCH; ++j)
            acc[j] += a * wcol[(size_t)ci*CO + j];
    }
    #pragma unroll
    for (int j = 0; j < WCH; ++j) acc[j] = fmaxf(acc[j], 0.f);
    #pragma unroll
    for (int off = KPTS/2; off > 0; off >>= 1)
        #pragma unroll
        for (int j = 0; j < WCH; ++j)
            acc[j] = fmaxf(acc[j], __shfl_xor(acc[j], off));
    if ((lane & (KPTS-1)) == 0) {
        int cent = (row0 + rl) / KPTS;
        float* op = fout + (size_t)cent*CO + wv*WCH;
        #pragma unroll
        for (int j4 = 0; j4 < WCH; j4 += 4) {
            float4 v;
            v.x = acc[j4+0]; v.y = acc[j4+1]; v.z = acc[j4+2]; v.w = acc[j4+3];
            *(float4*)(op + j4) = v;
        }
    }
}

// ---------------------------------------------------------------------------
// concat [R,3] ++ [R,CF] -> [R,3+CF]
// ---------------------------------------------------------------------------
__global__ void concat_kernel(const float* __restrict__ a, const float* __restrict__ f,
                              float* __restrict__ out, int R, int CF)
{
    int C = CF + 3;
    int t = blockIdx.x * blockDim.x + threadIdx.x;
    if (t >= R * C) return;
    int r = t / C, c = t % C;
    out[t] = (c < 3) ? a[r*3 + c] : f[(size_t)r * CF + (c - 3)];
}

// ---------------------------------------------------------------------------
// Tiled fp32 GEMM, 64x64 tile / 4x4 micro (small shapes + FC head).
// ---------------------------------------------------------------------------
template<int RELU, int HASB>
__global__ __launch_bounds__(256) void gemm_kernel(
    const float* __restrict__ A, const float* __restrict__ W,
    const float* __restrict__ bias, float* __restrict__ Cc,
    int Mr, int Nc, int Kd)
{
    __shared__ float As[64][17];
    __shared__ float Ws[16][65];
    int tx = threadIdx.x % 16;
    int ty = threadIdx.x / 16;
    int row0 = blockIdx.y * 64;
    int col0 = blockIdx.x * 64;
    float acc[4][4] = {};
    for (int k0 = 0; k0 < Kd; k0 += 16) {
        for (int t = threadIdx.x; t < 64*16; t += 256) {
            int r = t >> 4, kk = t & 15;
            int gr = row0 + r, gk = k0 + kk;
            As[r][kk] = (gr < Mr && gk < Kd) ? A[(size_t)gr * Kd + gk] : 0.f;
        }
        for (int t = threadIdx.x; t < 16*64; t += 256) {
            int kk = t >> 6, c = t & 63;
            int gk = k0 + kk, gc = col0 + c;
            Ws[kk][c] = (gk < Kd && gc < Nc) ? W[(size_t)gk * Nc + gc] : 0.f;
        }
        __syncthreads();
        #pragma unroll
        for (int kk = 0; kk < 16; ++kk) {
            float av[4], wv[4];
            #pragma unroll
            for (int i = 0; i < 4; i++) av[i] = As[ty*4+i][kk];
            #pragma unroll
            for (int j = 0; j < 4; j++) wv[j] = Ws[kk][tx*4+j];
            #pragma unroll
            for (int i = 0; i < 4; i++)
                #pragma unroll
                for (int j = 0; j < 4; j++)
                    acc[i][j] += av[i] * wv[j];
        }
        __syncthreads();
    }
    #pragma unroll
    for (int i = 0; i < 4; i++) {
        int gr = row0 + ty*4 + i;
        if (gr >= Mr) continue;
        #pragma unroll
        for (int j = 0; j < 4; j++) {
            int gc = col0 + tx*4 + j;
            if (gc >= Nc) continue;
            float v = acc[i][j];
            if (HASB) v += bias[gc];
            if (RELU) v = fmaxf(v, 0.f);
            Cc[(size_t)gr * Nc + gc] = v;
        }
    }
}

// ---------------------------------------------------------------------------
// Tiled fp32 GEMM, 64(M)x128(N) tile / 4x8 micro, 256 threads. Doubles the
// block count vs the 128x128 tile (4096x512 -> 256 blocks, x1024 -> 512) so
// the 256-CU grid is filled; ~13 KB LDS -> multiple blocks/CU. Strided
// fragment mapping (rows ty+16i, cols tx+16j) = conflict-free b32 reads.
// ---------------------------------------------------------------------------
template<int RELU, int HASB>
__global__ __launch_bounds__(256) void gemm_mn_kernel(
    const float* __restrict__ A, const float* __restrict__ W,
    const float* __restrict__ bias, float* __restrict__ Cc,
    int Mr, int Nc, int Kd)
{
    __shared__ float As[64][17];
    __shared__ float Ws[16][132];
    int tx = threadIdx.x % 16;
    int ty = threadIdx.x / 16;
    int row0 = blockIdx.y * 64;
    int col0 = blockIdx.x * 128;
    float acc[4][8] = {};
    for (int k0 = 0; k0 < Kd; k0 += 16) {
        for (int t = threadIdx.x; t < 64*16; t += 256) {
            int r = t >> 4, kk = t & 15;
            int gr = row0 + r, gk = k0 + kk;
            As[r][kk] = (gr < Mr && gk < Kd) ? A[(size_t)gr * Kd + gk] : 0.f;
        }
        for (int t = threadIdx.x; t < 16*128; t += 256) {
            int kk = t >> 7, c = t & 127;
            int gk = k0 + kk, gc = col0 + c;
            Ws[kk][c] = (gk < Kd && gc < Nc) ? W[(size_t)gk * Nc + gc] : 0.f;
        }
        __syncthreads();
        #pragma unroll
        for (int kk = 0; kk < 16; ++kk) {
            float av[4], wv[8];
            #pragma unroll
            for (int i = 0; i < 4; i++) av[i] = As[ty + 16*i][kk];
            #pragma unroll
            for (int j = 0; j < 8; j++) wv[j] = Ws[kk][tx + 16*j];
            #pragma unroll
            for (int i = 0; i < 4; i++)
                #pragma unroll
                for (int j = 0; j < 8; j++)
                    acc[i][j] += av[i] * wv[j];
        }
        __syncthreads();
    }
    #pragma unroll
    for (int i = 0; i < 4; i++) {
        int gr = row0 + ty + 16*i;
        if (gr >= Mr) continue;
        #pragma unroll
        for (int j = 0; j < 8; j++) {
            int gc = col0 + tx + 16*j;
            if (gc >= Nc) continue;
            float v = acc[i][j];
            if (HASB) v += bias[gc];
            if (RELU) v = fmaxf(v, 0.f);
            Cc[(size_t)gr * Nc + gc] = v;
        }
    }
}

// ---------------------------------------------------------------------------
// Max over P points: in [B,P,C] -> out [B,C]
// ---------------------------------------------------------------------------
__global__ void rowmax_kernel(const float* __restrict__ in, float* __restrict__ out,
                              int B, int P, int C)
{
    int t = blockIdx.x * blockDim.x + threadIdx.x;
    if (t >= B * C) return;
    int b = t / C, c = t % C;
    const float* p = in + (size_t)b * P * C + c;
    float mx = p[0];
    for (int i = 1; i < P; ++i) mx = fmaxf(mx, p[(size_t)i * C]);
    out[t] = mx;
}

// ---------------------------------------------------------------------------
extern "C" void kernel_launch(void* const* d_in, const int* in_sizes, int n_in,
                              void* d_out, int out_size, void* d_ws, size_t ws_size,
                              hipStream_t stream)
{
    const float* xyz    = (const float*)d_in[0];
    const float* points = (const float*)d_in[1];
    const float* w1a = (const float*)d_in[2];  const float* b1a = (const float*)d_in[3];
    const float* w1b = (const float*)d_in[4];  const float* b1b = (const float*)d_in[5];
    const float* w1c = (const float*)d_in[6];  const float* b1c = (const float*)d_in[7];
    const float* w2a = (const float*)d_in[8];  const float* b2a = (const float*)d_in[9];
    const float* w2b = (const float*)d_in[10]; const float* b2b = (const float*)d_in[11];
    const float* w2c = (const float*)d_in[12]; const float* b2c = (const float*)d_in[13];
    const float* w3a = (const float*)d_in[14]; const float* b3a = (const float*)d_in[15];
    const float* w3b = (const float*)d_in[16]; const float* b3b = (const float*)d_in[17];
    const float* w3c = (const float*)d_in[18]; const float* b3c = (const float*)d_in[19];
    const float* lin1 = (const float*)d_in[20];
    const float* lin2 = (const float*)d_in[21];
    const float* clsw = (const float*)d_in[22];
    const float* clsb = (const float*)d_in[23];

    char* ws = (char*)d_ws;
    size_t off = 0;
    auto alloc = [&](size_t bytes) -> void* {
        void* p = ws + off;
        off += (bytes + 255) & ~(size_t)255;
        return p;
    };
    int*   fps1 = (int*)  alloc((size_t)32*512*4);
    float* nx1  = (float*)alloc((size_t)32*512*3*4);
    int*   gi1  = (int*)  alloc((size_t)32*512*32*4);
    float* f1   = (float*)alloc((size_t)32*512*128*4);
    int*   fps2 = (int*)  alloc((size_t)32*128*4);
    float* nx2  = (float*)alloc((size_t)32*128*3*4);
    int*   gi2  = (int*)  alloc((size_t)32*128*64*4);
    float* f2   = (float*)alloc((size_t)32*128*256*4);
    float* g3   = (float*)alloc((size_t)4096*259*4);
    float* h3a  = (float*)alloc((size_t)4096*256*4);
    float* h3b  = (float*)alloc((size_t)4096*512*4);
    float* h3c  = (float*)alloc((size_t)4096*1024*4);
    float* f3   = (float*)alloc((size_t)32*1024*4);
    float* fc1  = (float*)alloc((size_t)32*512*4);
    float* fc2  = (float*)alloc((size_t)32*256*4);

    // Ping-pong activation buffers for the per-layer SA pipeline, sized from
    // the remaining workspace (chunked row processing keeps footprint bounded).
    size_t avail = (ws_size > off + 512) ? (ws_size - off - 512) : 0;
    size_t bufcap = avail / 2;
    if (bufcap > (size_t)140509184) bufcap = 140509184;  // >=134 MB -> 1 chunk for SA1
    float* bufA = (float*)alloc(bufcap);
    float* bufB = (float*)alloc(bufcap);

    // ---- SA1: N=1024 -> M=512, r=0.2, K=32, MLP 6->64->64->128
    fps_kernel<1024><<<32, 64, 0, stream>>>(xyz, 512, fps1, nx1);
    ballquery_kernel<<<ceil_div(32*512, 256), 256, 0, stream>>>(
        xyz, nx1, gi1, 32, 1024, 512, 32, (float)(0.2*0.2));
    {
        const int rows = 32*512*32;                     // 524288
        int ch = (int)((bufcap / (64*4)) & ~(size_t)63);
        if (ch > rows) ch = rows;
        if (ch < 64) ch = 64;
        for (int r0 = 0; r0 < rows; r0 += ch) {
            int rc = rows - r0 < ch ? rows - r0 : ch;
            int nb = rc / 64;
            sa_l1_kernel<3, 64, 32><<<nb, 256, 0, stream>>>(
                xyz, points, nx1, gi1, w1a, b1a, bufA, 1024, 512, r0, rc);
            layer_cm_kernel<64, 64><<<nb, 256, 0, stream>>>(
                bufA, w1b, b1b, bufB, rc);
            layer_max_cm_kernel<64, 128, 32><<<nb, 256, 0, stream>>>(
                bufB, w1c, b1c, f1, r0, rc);
        }
    }

    // ---- SA2: N=512 -> M=128, r=0.4, K=64, MLP 131->128->128->256
    fps_kernel<512><<<32, 64, 0, stream>>>(nx1, 128, fps2, nx2);
    ballquery_kernel<<<ceil_div(32*128, 256), 256, 0, stream>>>(
        nx1, nx2, gi2, 32, 512, 128, 64, (float)(0.4*0.4));
    {
        const int rows = 32*128*64;                     // 262144
        int ch = (int)((bufcap / (128*4)) & ~(size_t)63);
        if (ch > rows) ch = rows;
        if (ch < 64) ch = 64;
        for (int r0 = 0; r0 < rows; r0 += ch) {
            int rc = rows - r0 < ch ? rows - r0 : ch;
            int nb = rc / 64;
            sa_l1_kernel<128, 128, 64><<<nb, 256, 0, stream>>>(
                nx1, f1, nx2, gi2, w2a, b2a, bufA, 512, 128, r0, rc);
            layer_cm_kernel<128, 128><<<nb, 256, 0, stream>>>(
                bufA, w2b, b2b, bufB, rc);
            layer_max_cm_kernel<128, 256, 64><<<nb, 256, 0, stream>>>(
                bufB, w2c, b2c, f2, r0, rc);
        }
    }

    // ---- SA3 (group_all): concat [4096, 259] -> MLP 259->256->512->1024 -> max over 128
    concat_kernel<<<ceil_div(4096*259, 256), 256, 0, stream>>>(nx2, f2, g3, 4096, 256);
    {
        dim3 g(ceil_div(256, 64), ceil_div(4096, 64));
        gemm_kernel<1,1><<<g, 256, 0, stream>>>(g3, w3a, b3a, h3a, 4096, 256, 259);
    }
    {
        dim3 g(ceil_div(512, 128), ceil_div(4096, 64));
        gemm_mn_kernel<1,1><<<g, 256, 0, stream>>>(h3a, w3b, b3b, h3b, 4096, 512, 256);
    }
    {
        dim3 g(ceil_div(1024, 128), ceil_div(4096, 64));
        gemm_mn_kernel<1,1><<<g, 256, 0, stream>>>(h3b, w3c, b3c, h3c, 4096, 1024, 512);
    }
    rowmax_kernel<<<ceil_div(32*1024, 256), 256, 0, stream>>>(h3c, f3, 32, 128, 1024);

    // ---- FC head
    {
        dim3 g(ceil_div(512, 64), 1);
        gemm_kernel<1,0><<<g, 256, 0, stream>>>(f3, lin1, nullptr, fc1, 32, 512, 1024);
    }
    {
        dim3 g(ceil_div(256, 64), 1);
        gemm_kernel<1,0><<<g, 256, 0, stream>>>(fc1, lin2, nullptr, fc2, 32, 256, 512);
    }
    {
        dim3 g(1, 1);
        gemm_kernel<0,1><<<g, 256, 0, stream>>>(fc2, clsw, clsb, (float*)d_out, 32, 40, 256);
    }
}